// Round 1
// baseline (528.748 us; speedup 1.0000x reference)
//
#include <hip/hip_runtime.h>
#include <math.h>

#define BB 32
#define NN 128
#define DD 64
#define EE 5
#define TT 6   // 1+T iterations

__device__ __forceinline__ float sigmoidf_(float x) { return 1.f / (1.f + expf(-x)); }

// K1: msg[b,n,e,f] = prop[b,n,:] @ We[e,:,f] + be[e,f]
//     row[b,n,e] = msg . Wa_row[e,:], col[b,n,e] = msg . Wa_col[e,:]
// grid = B*N blocks, block = E*D = 320 threads (5 waves; wave == one expert e)
__global__ void k_msg(const float* __restrict__ prop, const float* __restrict__ We,
                      const float* __restrict__ be, const float* __restrict__ Wa,
                      float* __restrict__ msg, float* __restrict__ rowv,
                      float* __restrict__ colv)
{
    const int bn = blockIdx.x;            // b*N + n
    const int tid = threadIdx.x;          // 0..319
    const int e = tid >> 6, f = tid & 63;
    __shared__ float s_prop[DD];
    if (tid < DD) s_prop[tid] = prop[bn * DD + tid];
    __syncthreads();
    const float* w = We + e * DD * DD + f;   // stride D over d, lanes f coalesced
    float acc = be[e * DD + f];
    #pragma unroll
    for (int d = 0; d < DD; ++d) acc = fmaf(s_prop[d], w[d * DD], acc);
    msg[(bn * EE + e) * DD + f] = acc;

    float pr = acc * Wa[e * 2 * DD + f];
    float pc = acc * Wa[e * 2 * DD + DD + f];
    #pragma unroll
    for (int off = 32; off; off >>= 1) {
        pr += __shfl_xor(pr, off);
        pc += __shfl_xor(pc, off);
    }
    if (f == 0) { rowv[bn * EE + e] = pr; colv[bn * EE + e] = pc; }
}

// K2: scores[b,i,j,e] -> out slice t; merged[b,i,d] = sum_{j,e} scores*msg;
//     fused GRU epilogue updates prop[b,i,:] in place.
// grid = B*N blocks (one per (b,i)), block = 256 threads (4 waves)
__global__ void k_scores_gru(const float* __restrict__ msg, const float* __restrict__ rowv,
                             const float* __restrict__ colv, const float* __restrict__ ba,
                             const int* __restrict__ mask,
                             const float* __restrict__ Wr, const float* __restrict__ br,
                             const float* __restrict__ Wz, const float* __restrict__ bz,
                             const float* __restrict__ Wh, const float* __restrict__ bh,
                             float* __restrict__ out_t, float* __restrict__ prop)
{
    const int bi = blockIdx.x;            // b*N + i
    const int b = bi >> 7;
    const int i = bi & (NN - 1);
    const int tid = threadIdx.x;          // 0..255

    __shared__ float s_sc[NN * EE];       // 640 scores for this (b,i)
    __shared__ float s_red[4][DD];
    __shared__ float s_a[2 * DD];         // [merged | prop]
    __shared__ float s_rp[DD], s_z[DD], s_h[DD];

    // ---- scores (e fastest => je = j*E + e matches msg's (j,e) row order) ----
    const int maskbase = (b * NN + i) * NN;
    for (int je = tid; je < NN * EE; je += 256) {
        int j = je / EE, e = je - j * EE;
        float lg = rowv[bi * EE + e] + colv[(b * NN + j) * EE + e] + ba[e];
        float sc = sigmoidf_(lg) * (float)mask[maskbase + j];
        s_sc[je] = sc;
        out_t[(size_t)bi * (NN * EE) + je] = sc;
    }
    __syncthreads();

    // ---- merged[b,i,d] = sum_je s_sc[je] * msg[b, je, d] ----
    const int d = tid & 63, g = tid >> 6;
    const float* mb = msg + (size_t)b * (NN * EE) * DD;
    float acc = 0.f;
    const int je0 = g * (NN * EE / 4);    // 160 rows per wave
    #pragma unroll 4
    for (int je = je0; je < je0 + NN * EE / 4; ++je)
        acc = fmaf(s_sc[je], mb[je * DD + d], acc);   // 64 lanes coalesced
    s_red[g][d] = acc;
    __syncthreads();

    if (g == 0) {
        float m = s_red[0][d] + s_red[1][d] + s_red[2][d] + s_red[3][d];
        s_a[d] = m;                       // merged
        s_a[DD + d] = prop[bi * DD + d];  // prop (read before in-place write)
    }
    __syncthreads();

    // ---- GRU: r,z on waves 0/1; first-half of h on wave 2 ----
    if (g == 0) {
        float a_r = br[d];
        #pragma unroll
        for (int k = 0; k < 2 * DD; ++k) a_r = fmaf(s_a[k], Wr[k * DD + d], a_r);
        float r = sigmoidf_(a_r);
        s_rp[d] = r * s_a[DD + d];        // r * prop
    } else if (g == 1) {
        float a_z = bz[d];
        #pragma unroll
        for (int k = 0; k < 2 * DD; ++k) a_z = fmaf(s_a[k], Wz[k * DD + d], a_z);
        s_z[d] = sigmoidf_(a_z);
    } else if (g == 2) {
        float a_h = bh[d];
        #pragma unroll
        for (int k = 0; k < DD; ++k) a_h = fmaf(s_a[k], Wh[k * DD + d], a_h);
        s_h[d] = a_h;                     // partial h over merged half
    }
    __syncthreads();

    if (g == 0) {
        float a_h = s_h[d];
        #pragma unroll
        for (int k = 0; k < DD; ++k) a_h = fmaf(s_rp[k], Wh[(DD + k) * DD + d], a_h);
        float hh = tanhf(a_h);
        float z = s_z[d];
        float pn = (1.f - z) * s_a[DD + d] + z * hh;
        prop[bi * DD + d] = pn;
    }
}

extern "C" void kernel_launch(void* const* d_in, const int* in_sizes, int n_in,
                              void* d_out, int out_size, void* d_ws, size_t ws_size,
                              hipStream_t stream)
{
    const float* inputs = (const float*)d_in[0];
    const int*   mask   = (const int*)d_in[1];
    const float* We     = (const float*)d_in[2];
    const float* be     = (const float*)d_in[3];
    const float* Wa     = (const float*)d_in[4];
    const float* ba     = (const float*)d_in[5];
    const float* Wr     = (const float*)d_in[6];
    const float* br     = (const float*)d_in[7];
    const float* Wz     = (const float*)d_in[8];
    const float* bz     = (const float*)d_in[9];
    const float* Wh     = (const float*)d_in[10];
    const float* bh     = (const float*)d_in[11];
    float* out = (float*)d_out;

    float* prop = (float*)d_ws;                         // B*N*D
    float* msg  = prop + BB * NN * DD;                  // B*N*E*D
    float* rowv = msg + BB * NN * EE * DD;              // B*N*E
    float* colv = rowv + BB * NN * EE;                  // B*N*E

    hipMemcpyAsync(prop, inputs, (size_t)BB * NN * DD * sizeof(float),
                   hipMemcpyDeviceToDevice, stream);

    for (int t = 0; t < TT; ++t) {
        k_msg<<<BB * NN, EE * DD, 0, stream>>>(prop, We, be, Wa, msg, rowv, colv);
        k_scores_gru<<<BB * NN, 256, 0, stream>>>(msg, rowv, colv, ba, mask,
                                                  Wr, br, Wz, bz, Wh, bh,
                                                  out + (size_t)t * BB * NN * NN * EE,
                                                  prop);
    }
}

// Round 2
// 314.787 us; speedup vs baseline: 1.6797x; 1.6797x over previous
//
#include <hip/hip_runtime.h>
#include <math.h>

#define BB 32
#define NN 128
#define DD 64
#define EE 5
#define TT 6          // 1+T iterations
#define NE (NN*EE)    // 640

__device__ __forceinline__ float fsig(float x) {
    float t = __expf(-x);
    return __fdividef(1.f, 1.f + t);
}
__device__ __forceinline__ float ftanh(float x) {
    float xc = fminf(fmaxf(x, -15.f), 15.f);
    float t = __expf(-2.f * xc);
    return 1.f - __fdividef(2.f * t, 1.f + t);
}

// K1: msg + row/col projections, 4 n-rows per block.
// block = 320 (5 waves; wave == expert e), grid = B*N/4 = 1024
__global__ void __launch_bounds__(320) k_msg(
    const float* __restrict__ prop, const float* __restrict__ We,
    const float* __restrict__ be, const float* __restrict__ Wa,
    float* __restrict__ msg, float* __restrict__ rowv, float* __restrict__ colv)
{
    const int bn0 = blockIdx.x * 4;
    const int tid = threadIdx.x;
    const int e = tid >> 6, f = tid & 63;
    __shared__ float s_pt[DD][4];          // prop transposed: [d][q]
    if (tid < 256) {
        int q = tid >> 6, d = tid & 63;
        s_pt[d][q] = prop[(bn0 + q) * DD + d];
    }
    __syncthreads();

    const float* w = We + e * DD * DD + f;
    const float bias = be[e * DD + f];
    float a0 = bias, a1 = bias, a2 = bias, a3 = bias;
    #pragma unroll 8
    for (int d = 0; d < DD; ++d) {
        float wv = w[d * DD];
        float4 p = *(const float4*)&s_pt[d][0];   // broadcast b128
        a0 = fmaf(p.x, wv, a0);
        a1 = fmaf(p.y, wv, a1);
        a2 = fmaf(p.z, wv, a2);
        a3 = fmaf(p.w, wv, a3);
    }
    msg[((size_t)(bn0+0)*EE + e)*DD + f] = a0;
    msg[((size_t)(bn0+1)*EE + e)*DD + f] = a1;
    msg[((size_t)(bn0+2)*EE + e)*DD + f] = a2;
    msg[((size_t)(bn0+3)*EE + e)*DD + f] = a3;

    const float war = Wa[e*2*DD + f], wac = Wa[e*2*DD + DD + f];
    float r0=a0*war, r1=a1*war, r2=a2*war, r3=a3*war;
    float c0=a0*wac, c1=a1*wac, c2=a2*wac, c3=a3*wac;
    #pragma unroll
    for (int off = 32; off; off >>= 1) {
        r0 += __shfl_xor(r0,off); r1 += __shfl_xor(r1,off);
        r2 += __shfl_xor(r2,off); r3 += __shfl_xor(r3,off);
        c0 += __shfl_xor(c0,off); c1 += __shfl_xor(c1,off);
        c2 += __shfl_xor(c2,off); c3 += __shfl_xor(c3,off);
    }
    if (f == 0) {
        rowv[(bn0+0)*EE+e]=r0; rowv[(bn0+1)*EE+e]=r1;
        rowv[(bn0+2)*EE+e]=r2; rowv[(bn0+3)*EE+e]=r3;
        colv[(bn0+0)*EE+e]=c0; colv[(bn0+1)*EE+e]=c1;
        colv[(bn0+2)*EE+e]=c2; colv[(bn0+3)*EE+e]=c3;
    }
}

// K2: scores -> out, merged GEMV, fused GRU. 4 i-rows per block.
// block = 256 (4 waves), grid = B*N/4 = 1024
__global__ void __launch_bounds__(256) k_scores_gru(
    const float* __restrict__ msg, const float* __restrict__ rowv,
    const float* __restrict__ colv, const float* __restrict__ ba,
    const int* __restrict__ mask,
    const float* __restrict__ Wr, const float* __restrict__ br,
    const float* __restrict__ Wz, const float* __restrict__ bz,
    const float* __restrict__ Wh, const float* __restrict__ bh,
    float* __restrict__ out_t, float* __restrict__ prop)
{
    const int bi0 = blockIdx.x * 4;
    const int b = bi0 >> 7;
    const int tid = threadIdx.x;
    const int d = tid & 63, g = tid >> 6;   // lane, wave; (q,d) phases use q=g

    __shared__ float s_sc[NE][4];           // scores [je][q]  (10 KB)
    __shared__ float s_part[4][4][DD];      // partials [g][q][d] (reused)
    __shared__ float s_part2[4][4][DD];
    __shared__ float s_mt[DD][4];           // merged transposed [d][q]
    __shared__ float s_pt[DD][4];           // prop
    __shared__ float s_rpt[DD][4];          // r*prop

    // ---- scores ----
    for (int qq = 0; qq < 4; ++qq) {
        const int bi = bi0 + qq;
        const float* rv = rowv + bi * EE;
        const int mbase = (b * NN + (bi & (NN-1))) * NN;
        for (int je = tid; je < NE; je += 256) {
            int j = je / EE, e = je - j * EE;
            float lg = rv[e] + colv[b * NE + je] + ba[e];
            float sc = fsig(lg) * (float)mask[mbase + j];
            s_sc[je][qq] = sc;
            out_t[(size_t)bi * NE + je] = sc;
        }
    }
    __syncthreads();

    // ---- merged partials: wave g covers je in [g*160, g*160+160) ----
    {
        const float* mb = msg + (size_t)b * NE * DD;
        float a0=0.f, a1=0.f, a2=0.f, a3=0.f;
        const int je0 = g * 160;
        #pragma unroll 4
        for (int je = je0; je < je0 + 160; ++je) {
            float m = mb[(size_t)je * DD + d];
            float4 sc = *(const float4*)&s_sc[je][0];   // broadcast b128
            a0 = fmaf(sc.x, m, a0); a1 = fmaf(sc.y, m, a1);
            a2 = fmaf(sc.z, m, a2); a3 = fmaf(sc.w, m, a3);
        }
        s_part[g][0][d]=a0; s_part[g][1][d]=a1;
        s_part[g][2][d]=a2; s_part[g][3][d]=a3;
    }
    __syncthreads();

    // ---- combine merged; load prop (thread = (q=g, d)) ----
    float p_reg, m_reg;
    {
        m_reg = s_part[0][g][d] + s_part[1][g][d] + s_part[2][g][d] + s_part[3][g][d];
        p_reg = prop[(bi0 + g) * DD + d];
        s_mt[d][g] = m_reg;
        s_pt[d][g] = p_reg;
    }
    __syncthreads();

    // ---- gates r,z: wave g covers k-quarter of 128; weights read once/block ----
    {
        const float* vsrc = (g & 2) ? &s_pt[0][0] : &s_mt[0][0];
        const int kbase = (g & 2) ? 64 : 0;
        const int k0 = (g & 1) * 32;
        float r0=0,r1=0,r2=0,r3=0, z0=0,z1=0,z2=0,z3=0;
        #pragma unroll 8
        for (int kk = 0; kk < 32; ++kk) {
            int k = k0 + kk;
            int kg = kbase + k;
            float wr = Wr[kg * DD + d];
            float wz = Wz[kg * DD + d];
            float4 v = *(const float4*)&vsrc[k * 4];    // broadcast b128
            r0=fmaf(v.x,wr,r0); r1=fmaf(v.y,wr,r1); r2=fmaf(v.z,wr,r2); r3=fmaf(v.w,wr,r3);
            z0=fmaf(v.x,wz,z0); z1=fmaf(v.y,wz,z1); z2=fmaf(v.z,wz,z2); z3=fmaf(v.w,wz,z3);
        }
        s_part[g][0][d]=r0; s_part[g][1][d]=r1; s_part[g][2][d]=r2; s_part[g][3][d]=r3;
        s_part2[g][0][d]=z0; s_part2[g][1][d]=z1; s_part2[g][2][d]=z2; s_part2[g][3][d]=z3;
    }
    __syncthreads();

    // ---- combine r,z; r*prop to LDS; z stays in register ----
    float z_reg;
    {
        float ar = br[d] + s_part[0][g][d] + s_part[1][g][d] + s_part[2][g][d] + s_part[3][g][d];
        float az = bz[d] + s_part2[0][g][d] + s_part2[1][g][d] + s_part2[2][g][d] + s_part2[3][g][d];
        float r = fsig(ar);
        z_reg = fsig(az);
        s_rpt[d][g] = r * p_reg;
    }
    __syncthreads();

    // ---- gate h: same k-split; [merged | r*prop] ----
    {
        const float* vsrc = (g & 2) ? &s_rpt[0][0] : &s_mt[0][0];
        const int kbase = (g & 2) ? 64 : 0;
        const int k0 = (g & 1) * 32;
        float h0=0,h1=0,h2=0,h3=0;
        #pragma unroll 8
        for (int kk = 0; kk < 32; ++kk) {
            int k = k0 + kk;
            int kg = kbase + k;
            float wh = Wh[kg * DD + d];
            float4 v = *(const float4*)&vsrc[k * 4];
            h0=fmaf(v.x,wh,h0); h1=fmaf(v.y,wh,h1); h2=fmaf(v.z,wh,h2); h3=fmaf(v.w,wh,h3);
        }
        s_part[g][0][d]=h0; s_part[g][1][d]=h1; s_part[g][2][d]=h2; s_part[g][3][d]=h3;
    }
    __syncthreads();

    // ---- finish: h, prop update ----
    {
        float ah = bh[d] + s_part[0][g][d] + s_part[1][g][d] + s_part[2][g][d] + s_part[3][g][d];
        float hh = ftanh(ah);
        float pn = (1.f - z_reg) * p_reg + z_reg * hh;
        prop[(bi0 + g) * DD + d] = pn;
    }
}

extern "C" void kernel_launch(void* const* d_in, const int* in_sizes, int n_in,
                              void* d_out, int out_size, void* d_ws, size_t ws_size,
                              hipStream_t stream)
{
    const float* inputs = (const float*)d_in[0];
    const int*   mask   = (const int*)d_in[1];
    const float* We     = (const float*)d_in[2];
    const float* be     = (const float*)d_in[3];
    const float* Wa     = (const float*)d_in[4];
    const float* ba     = (const float*)d_in[5];
    const float* Wr     = (const float*)d_in[6];
    const float* br     = (const float*)d_in[7];
    const float* Wz     = (const float*)d_in[8];
    const float* bz     = (const float*)d_in[9];
    const float* Wh     = (const float*)d_in[10];
    const float* bh     = (const float*)d_in[11];
    float* out = (float*)d_out;

    float* prop = (float*)d_ws;                         // B*N*D
    float* msg  = prop + BB * NN * DD;                  // B*N*E*D
    float* rowv = msg + (size_t)BB * NN * EE * DD;      // B*N*E
    float* colv = rowv + BB * NN * EE;                  // B*N*E

    hipMemcpyAsync(prop, inputs, (size_t)BB * NN * DD * sizeof(float),
                   hipMemcpyDeviceToDevice, stream);

    for (int t = 0; t < TT; ++t) {
        k_msg<<<BB * NN / 4, EE * DD, 0, stream>>>(prop, We, be, Wa, msg, rowv, colv);
        k_scores_gru<<<BB * NN / 4, 256, 0, stream>>>(msg, rowv, colv, ba, mask,
                                                      Wr, br, Wz, bz, Wh, bh,
                                                      out + (size_t)t * BB * NN * NN * EE,
                                                      prop);
    }
}

// Round 4
// 314.006 us; speedup vs baseline: 1.6839x; 1.0025x over previous
//
#include <hip/hip_runtime.h>
#include <hip/hip_cooperative_groups.h>
#include <math.h>

namespace cg = cooperative_groups;

#define BB 32
#define NN 128
#define DD 64
#define EE 5
#define TT 6          // 1+T iterations
#define NE (NN*EE)    // 640
#define MSG_SZ ((size_t)BB*NN*EE*DD)   // 1310720
#define COL_SZ ((size_t)BB*NN*EE)      // 20480

__device__ __forceinline__ float fsig(float x) {
    float t = __expf(-x);
    return __fdividef(1.f, 1.f + t);
}
__device__ __forceinline__ float ftanh_(float x) {
    float xc = fminf(fmaxf(x, -15.f), 15.f);
    float t = __expf(-2.f * xc);
    return 1.f - __fdividef(2.f * t, 1.f + t);
}

// ========================= fused cooperative kernel =========================
// One block owns 4 (b,i) rows for the whole recurrence. block = 256 (4 waves),
// grid = B*N/4 = 1024 cooperative blocks (4 blocks/CU on 256 CUs).
__global__ void __launch_bounds__(256, 4) k_fused(
    const float* __restrict__ inputs, const int* __restrict__ mask,
    const float* __restrict__ We, const float* __restrict__ be,
    const float* __restrict__ Wa, const float* __restrict__ ba,
    const float* __restrict__ Wr, const float* __restrict__ br,
    const float* __restrict__ Wz, const float* __restrict__ bz,
    const float* __restrict__ Wh, const float* __restrict__ bh,
    float* __restrict__ out,
    float* __restrict__ msg0, float* __restrict__ msg1,
    float* __restrict__ colv0, float* __restrict__ colv1)
{
    cg::grid_group grid = cg::this_grid();
    const int bi0 = blockIdx.x * 4;
    const int b = bi0 >> 7;
    const int tid = threadIdx.x;
    const int g = tid >> 6;        // wave 0..3
    const int f = tid & 63;        // lane

    __shared__ float s_pt[DD][4];         // prop transposed [d][q] (lives all iters)
    __shared__ float s_mt[DD][4];         // merged transposed
    __shared__ float s_rpt[DD][4];        // r*prop
    __shared__ float s_sc[NE][4];         // scores [je][q]
    __shared__ float s_part[4][4][DD];
    __shared__ float s_part2[4][4][DD];
    __shared__ float s_rv[4][EE];         // row logits for own 4 rows

    s_pt[f][g] = inputs[(bi0 + g) * DD + f];
    __syncthreads();

    const bool dbuf = (msg0 != msg1);

    for (int t = 0; t < TT; ++t) {
        float* msgW = (t & 1) ? msg1 : msg0;
        float* colW = (t & 1) ? colv1 : colv0;
        if (!dbuf && t > 0) grid.sync();   // WAR guard when single-buffered

        // ============ Phase A: msg(t) for own 4 rows (experts e = g, g+4) ============
        for (int e = g; e < EE; e += 4) {
            const float* w = We + e * DD * DD + f;
            const float bias = be[e * DD + f];
            float a0 = bias, a1 = bias, a2 = bias, a3 = bias;
            #pragma unroll 8
            for (int k = 0; k < DD; ++k) {
                float wv = w[k * DD];
                float4 p = *(const float4*)&s_pt[k][0];
                a0 = fmaf(p.x, wv, a0); a1 = fmaf(p.y, wv, a1);
                a2 = fmaf(p.z, wv, a2); a3 = fmaf(p.w, wv, a3);
            }
            msgW[((size_t)(bi0+0)*EE + e)*DD + f] = a0;
            msgW[((size_t)(bi0+1)*EE + e)*DD + f] = a1;
            msgW[((size_t)(bi0+2)*EE + e)*DD + f] = a2;
            msgW[((size_t)(bi0+3)*EE + e)*DD + f] = a3;

            const float war = Wa[e*2*DD + f], wac = Wa[e*2*DD + DD + f];
            float r0=a0*war, r1=a1*war, r2=a2*war, r3=a3*war;
            float c0=a0*wac, c1=a1*wac, c2=a2*wac, c3=a3*wac;
            #pragma unroll
            for (int off = 32; off; off >>= 1) {
                r0 += __shfl_xor(r0,off); r1 += __shfl_xor(r1,off);
                r2 += __shfl_xor(r2,off); r3 += __shfl_xor(r3,off);
                c0 += __shfl_xor(c0,off); c1 += __shfl_xor(c1,off);
                c2 += __shfl_xor(c2,off); c3 += __shfl_xor(c3,off);
            }
            if (f == 0) {
                s_rv[0][e]=r0; s_rv[1][e]=r1; s_rv[2][e]=r2; s_rv[3][e]=r3;
                colW[(bi0+0)*EE+e]=c0; colW[(bi0+1)*EE+e]=c1;
                colW[(bi0+2)*EE+e]=c2; colW[(bi0+3)*EE+e]=c3;
            }
        }
        grid.sync();                         // msg/colv of whole batch ready

        const float* msgR = msgW;
        const float* colR = colW;
        float* out_t = out + (size_t)t * BB * NN * NE;

        // ============ Phase B: scores -> out, merged, GRU ============
        for (int qq = 0; qq < 4; ++qq) {
            const int bi = bi0 + qq;
            const int mbase = (b * NN + (bi & (NN-1))) * NN;
            for (int je = tid; je < NE; je += 256) {
                int j = je / EE, e = je - j * EE;
                float lg = s_rv[qq][e] + colR[b * NE + je] + ba[e];
                float sc = fsig(lg) * (float)mask[mbase + j];
                s_sc[je][qq] = sc;
                out_t[(size_t)bi * NE + je] = sc;
            }
        }
        __syncthreads();

        // merged partials: wave g covers je in [g*160, g*160+160)
        {
            const float* mb = msgR + (size_t)b * NE * DD;
            float a0=0.f, a1=0.f, a2=0.f, a3=0.f;
            const int je0 = g * 160;
            #pragma unroll 4
            for (int je = je0; je < je0 + 160; ++je) {
                float m = mb[(size_t)je * DD + f];
                float4 sc = *(const float4*)&s_sc[je][0];
                a0 = fmaf(sc.x, m, a0); a1 = fmaf(sc.y, m, a1);
                a2 = fmaf(sc.z, m, a2); a3 = fmaf(sc.w, m, a3);
            }
            s_part[g][0][f]=a0; s_part[g][1][f]=a1;
            s_part[g][2][f]=a2; s_part[g][3][f]=a3;
        }
        __syncthreads();

        const int d = f;
        float p_reg, z_reg;
        {
            float m_reg = s_part[0][g][d] + s_part[1][g][d]
                        + s_part[2][g][d] + s_part[3][g][d];
            p_reg = s_pt[d][g];
            s_mt[d][g] = m_reg;
        }
        __syncthreads();

        // gates r,z: wave g covers a k-quarter; weights read once per block
        {
            const float* vsrc = (g & 2) ? &s_pt[0][0] : &s_mt[0][0];
            const int kbase = (g & 2) ? 64 : 0;
            const int k0 = (g & 1) * 32;
            float r0=0,r1=0,r2=0,r3=0, z0=0,z1=0,z2=0,z3=0;
            #pragma unroll 8
            for (int kk = 0; kk < 32; ++kk) {
                int k = k0 + kk;
                int kg = kbase + k;
                float wr = Wr[kg * DD + d];
                float wz = Wz[kg * DD + d];
                float4 v = *(const float4*)&vsrc[k * 4];
                r0=fmaf(v.x,wr,r0); r1=fmaf(v.y,wr,r1); r2=fmaf(v.z,wr,r2); r3=fmaf(v.w,wr,r3);
                z0=fmaf(v.x,wz,z0); z1=fmaf(v.y,wz,z1); z2=fmaf(v.z,wz,z2); z3=fmaf(v.w,wz,z3);
            }
            s_part[g][0][d]=r0; s_part[g][1][d]=r1; s_part[g][2][d]=r2; s_part[g][3][d]=r3;
            s_part2[g][0][d]=z0; s_part2[g][1][d]=z1; s_part2[g][2][d]=z2; s_part2[g][3][d]=z3;
        }
        __syncthreads();

        {
            float ar = br[d] + s_part[0][g][d] + s_part[1][g][d] + s_part[2][g][d] + s_part[3][g][d];
            float az = bz[d] + s_part2[0][g][d] + s_part2[1][g][d] + s_part2[2][g][d] + s_part2[3][g][d];
            float r = fsig(ar);
            z_reg = fsig(az);
            s_rpt[d][g] = r * p_reg;
        }
        __syncthreads();

        // gate h: same k-split over [merged | r*prop]
        {
            const float* vsrc = (g & 2) ? &s_rpt[0][0] : &s_mt[0][0];
            const int kbase = (g & 2) ? 64 : 0;
            const int k0 = (g & 1) * 32;
            float h0=0,h1=0,h2=0,h3=0;
            #pragma unroll 8
            for (int kk = 0; kk < 32; ++kk) {
                int k = k0 + kk;
                int kg = kbase + k;
                float wh = Wh[kg * DD + d];
                float4 v = *(const float4*)&vsrc[k * 4];
                h0=fmaf(v.x,wh,h0); h1=fmaf(v.y,wh,h1); h2=fmaf(v.z,wh,h2); h3=fmaf(v.w,wh,h3);
            }
            s_part[g][0][d]=h0; s_part[g][1][d]=h1; s_part[g][2][d]=h2; s_part[g][3][d]=h3;
        }
        __syncthreads();

        {
            float ah = bh[d] + s_part[0][g][d] + s_part[1][g][d] + s_part[2][g][d] + s_part[3][g][d];
            float hh = ftanh_(ah);
            float pn = (1.f - z_reg) * p_reg + z_reg * hh;
            s_pt[d][g] = pn;        // prop stays in LDS for next iteration
        }
        __syncthreads();
    }
}

// ========================= fallback path (round-2 proven) =========================
__global__ void __launch_bounds__(320) k_msg(
    const float* __restrict__ prop, const float* __restrict__ We,
    const float* __restrict__ be, const float* __restrict__ Wa,
    float* __restrict__ msg, float* __restrict__ rowv, float* __restrict__ colv)
{
    const int bn0 = blockIdx.x * 4;
    const int tid = threadIdx.x;
    const int e = tid >> 6, f = tid & 63;
    __shared__ float s_pt[DD][4];
    if (tid < 256) {
        int q = tid >> 6, d = tid & 63;
        s_pt[d][q] = prop[(bn0 + q) * DD + d];
    }
    __syncthreads();

    const float* w = We + e * DD * DD + f;
    const float bias = be[e * DD + f];
    float a0 = bias, a1 = bias, a2 = bias, a3 = bias;
    #pragma unroll 8
    for (int d = 0; d < DD; ++d) {
        float wv = w[d * DD];
        float4 p = *(const float4*)&s_pt[d][0];
        a0 = fmaf(p.x, wv, a0); a1 = fmaf(p.y, wv, a1);
        a2 = fmaf(p.z, wv, a2); a3 = fmaf(p.w, wv, a3);
    }
    msg[((size_t)(bn0+0)*EE + e)*DD + f] = a0;
    msg[((size_t)(bn0+1)*EE + e)*DD + f] = a1;
    msg[((size_t)(bn0+2)*EE + e)*DD + f] = a2;
    msg[((size_t)(bn0+3)*EE + e)*DD + f] = a3;

    const float war = Wa[e*2*DD + f], wac = Wa[e*2*DD + DD + f];
    float r0=a0*war, r1=a1*war, r2=a2*war, r3=a3*war;
    float c0=a0*wac, c1=a1*wac, c2=a2*wac, c3=a3*wac;
    #pragma unroll
    for (int off = 32; off; off >>= 1) {
        r0 += __shfl_xor(r0,off); r1 += __shfl_xor(r1,off);
        r2 += __shfl_xor(r2,off); r3 += __shfl_xor(r3,off);
        c0 += __shfl_xor(c0,off); c1 += __shfl_xor(c1,off);
        c2 += __shfl_xor(c2,off); c3 += __shfl_xor(c3,off);
    }
    if (f == 0) {
        rowv[(bn0+0)*EE+e]=r0; rowv[(bn0+1)*EE+e]=r1;
        rowv[(bn0+2)*EE+e]=r2; rowv[(bn0+3)*EE+e]=r3;
        colv[(bn0+0)*EE+e]=c0; colv[(bn0+1)*EE+e]=c1;
        colv[(bn0+2)*EE+e]=c2; colv[(bn0+3)*EE+e]=c3;
    }
}

__global__ void __launch_bounds__(256) k_scores_gru(
    const float* __restrict__ msg, const float* __restrict__ rowv,
    const float* __restrict__ colv, const float* __restrict__ ba,
    const int* __restrict__ mask,
    const float* __restrict__ Wr, const float* __restrict__ br,
    const float* __restrict__ Wz, const float* __restrict__ bz,
    const float* __restrict__ Wh, const float* __restrict__ bh,
    float* __restrict__ out_t, float* __restrict__ prop)
{
    const int bi0 = blockIdx.x * 4;
    const int b = bi0 >> 7;
    const int tid = threadIdx.x;
    const int d = tid & 63, g = tid >> 6;

    __shared__ float s_sc[NE][4];
    __shared__ float s_part[4][4][DD];
    __shared__ float s_part2[4][4][DD];
    __shared__ float s_mt[DD][4];
    __shared__ float s_pt[DD][4];
    __shared__ float s_rpt[DD][4];

    for (int qq = 0; qq < 4; ++qq) {
        const int bi = bi0 + qq;
        const float* rv = rowv + bi * EE;
        const int mbase = (b * NN + (bi & (NN-1))) * NN;
        for (int je = tid; je < NE; je += 256) {
            int j = je / EE, e = je - j * EE;
            float lg = rv[e] + colv[b * NE + je] + ba[e];
            float sc = fsig(lg) * (float)mask[mbase + j];
            s_sc[je][qq] = sc;
            out_t[(size_t)bi * NE + je] = sc;
        }
    }
    __syncthreads();

    {
        const float* mb = msg + (size_t)b * NE * DD;
        float a0=0.f, a1=0.f, a2=0.f, a3=0.f;
        const int je0 = g * 160;
        #pragma unroll 4
        for (int je = je0; je < je0 + 160; ++je) {
            float m = mb[(size_t)je * DD + d];
            float4 sc = *(const float4*)&s_sc[je][0];
            a0 = fmaf(sc.x, m, a0); a1 = fmaf(sc.y, m, a1);
            a2 = fmaf(sc.z, m, a2); a3 = fmaf(sc.w, m, a3);
        }
        s_part[g][0][d]=a0; s_part[g][1][d]=a1;
        s_part[g][2][d]=a2; s_part[g][3][d]=a3;
    }
    __syncthreads();

    float p_reg, m_reg;
    {
        m_reg = s_part[0][g][d] + s_part[1][g][d] + s_part[2][g][d] + s_part[3][g][d];
        p_reg = prop[(bi0 + g) * DD + d];
        s_mt[d][g] = m_reg;
        s_pt[d][g] = p_reg;
    }
    __syncthreads();

    {
        const float* vsrc = (g & 2) ? &s_pt[0][0] : &s_mt[0][0];
        const int kbase = (g & 2) ? 64 : 0;
        const int k0 = (g & 1) * 32;
        float r0=0,r1=0,r2=0,r3=0, z0=0,z1=0,z2=0,z3=0;
        #pragma unroll 8
        for (int kk = 0; kk < 32; ++kk) {
            int k = k0 + kk;
            int kg = kbase + k;
            float wr = Wr[kg * DD + d];
            float wz = Wz[kg * DD + d];
            float4 v = *(const float4*)&vsrc[k * 4];
            r0=fmaf(v.x,wr,r0); r1=fmaf(v.y,wr,r1); r2=fmaf(v.z,wr,r2); r3=fmaf(v.w,wr,r3);
            z0=fmaf(v.x,wz,z0); z1=fmaf(v.y,wz,z1); z2=fmaf(v.z,wz,z2); z3=fmaf(v.w,wz,z3);
        }
        s_part[g][0][d]=r0; s_part[g][1][d]=r1; s_part[g][2][d]=r2; s_part[g][3][d]=r3;
        s_part2[g][0][d]=z0; s_part2[g][1][d]=z1; s_part2[g][2][d]=z2; s_part2[g][3][d]=z3;
    }
    __syncthreads();

    float z_reg;
    {
        float ar = br[d] + s_part[0][g][d] + s_part[1][g][d] + s_part[2][g][d] + s_part[3][g][d];
        float az = bz[d] + s_part2[0][g][d] + s_part2[1][g][d] + s_part2[2][g][d] + s_part2[3][g][d];
        float r = fsig(ar);
        z_reg = fsig(az);
        s_rpt[d][g] = r * p_reg;
    }
    __syncthreads();

    {
        const float* vsrc = (g & 2) ? &s_rpt[0][0] : &s_mt[0][0];
        const int kbase = (g & 2) ? 64 : 0;
        const int k0 = (g & 1) * 32;
        float h0=0,h1=0,h2=0,h3=0;
        #pragma unroll 8
        for (int kk = 0; kk < 32; ++kk) {
            int k = k0 + kk;
            int kg = kbase + k;
            float wh = Wh[kg * DD + d];
            float4 v = *(const float4*)&vsrc[k * 4];
            h0=fmaf(v.x,wh,h0); h1=fmaf(v.y,wh,h1); h2=fmaf(v.z,wh,h2); h3=fmaf(v.w,wh,h3);
        }
        s_part[g][0][d]=h0; s_part[g][1][d]=h1; s_part[g][2][d]=h2; s_part[g][3][d]=h3;
    }
    __syncthreads();

    {
        float ah = bh[d] + s_part[0][g][d] + s_part[1][g][d] + s_part[2][g][d] + s_part[3][g][d];
        float hh = ftanh_(ah);
        float pn = (1.f - z_reg) * p_reg + z_reg * hh;
        prop[(bi0 + g) * DD + d] = pn;
    }
}

extern "C" void kernel_launch(void* const* d_in, const int* in_sizes, int n_in,
                              void* d_out, int out_size, void* d_ws, size_t ws_size,
                              hipStream_t stream)
{
    const float* inputs = (const float*)d_in[0];
    const int*   mask   = (const int*)d_in[1];
    const float* We     = (const float*)d_in[2];
    const float* be     = (const float*)d_in[3];
    const float* Wa     = (const float*)d_in[4];
    const float* ba     = (const float*)d_in[5];
    const float* Wr     = (const float*)d_in[6];
    const float* br     = (const float*)d_in[7];
    const float* Wz     = (const float*)d_in[8];
    const float* bz     = (const float*)d_in[9];
    const float* Wh     = (const float*)d_in[10];
    const float* bh     = (const float*)d_in[11];
    float* out = (float*)d_out;
    float* ws = (float*)d_ws;

    // ---- capture-safe host-side occupancy check (same work every call) ----
    int occ = 0, ncu = 0, dev = 0;
    bool coop = (hipGetDevice(&dev) == hipSuccess)
             && (hipDeviceGetAttribute(&ncu, hipDeviceAttributeMultiprocessorCount, dev) == hipSuccess)
             && (hipOccupancyMaxActiveBlocksPerMultiprocessor(&occ, (const void*)k_fused, 256, 0) == hipSuccess)
             && ((long)occ * ncu >= BB * NN / 4);

    if (coop) {
        float* msg0  = ws;
        float* colv0 = msg0 + MSG_SZ;
        float* msg1  = msg0;
        float* colv1 = colv0;
        if (ws_size >= 2 * (MSG_SZ + COL_SZ) * sizeof(float)) {
            msg1  = colv0 + COL_SZ;        // double-buffer: 1 grid sync per iteration
            colv1 = msg1 + MSG_SZ;
        }
        void* args[] = {
            (void*)&inputs, (void*)&mask, (void*)&We, (void*)&be, (void*)&Wa, (void*)&ba,
            (void*)&Wr, (void*)&br, (void*)&Wz, (void*)&bz, (void*)&Wh, (void*)&bh,
            (void*)&out, (void*)&msg0, (void*)&msg1, (void*)&colv0, (void*)&colv1
        };
        hipError_t err = hipLaunchCooperativeKernel((const void*)k_fused,
                            dim3(BB * NN / 4), dim3(256), args, 0, stream);
        if (err == hipSuccess) return;
        // fall through to fallback on launch failure
    }

    // ---- fallback: proven round-2 two-kernel path ----
    float* prop = ws;                                   // B*N*D
    float* msg  = prop + (size_t)BB * NN * DD;          // B*N*E*D
    float* rowv = msg + MSG_SZ;                         // B*N*E
    float* colv = rowv + COL_SZ;                        // B*N*E

    hipMemcpyAsync(prop, inputs, (size_t)BB * NN * DD * sizeof(float),
                   hipMemcpyDeviceToDevice, stream);

    for (int t = 0; t < TT; ++t) {
        k_msg<<<BB * NN / 4, EE * DD, 0, stream>>>(prop, We, be, Wa, msg, rowv, colv);
        k_scores_gru<<<BB * NN / 4, 256, 0, stream>>>(msg, rowv, colv, ba, mask,
                                                      Wr, br, Wz, bz, Wh, bh,
                                                      out + (size_t)t * BB * NN * NE,
                                                      prop);
    }
}